// Round 7
// baseline (167.292 us; speedup 1.0000x reference)
//
#include <hip/hip_runtime.h>
#include <hip/hip_bf16.h>

#define FEAT   1024
#define HID    256
#define TSTEPS 24
#define NCLS   10

typedef unsigned int u32;
typedef unsigned long long u64;
typedef unsigned short u16;
typedef float v2f __attribute__((ext_vector_type(2)));

// ---- workspace layout (float offsets).
// W1T: [1025][256] (W1^T + zero row at col 1024).
// W23: [257][512]  INTERLEAVED W2^T | W3^T per column (col c: floats [0,256) =
//      W2T row c, [256,512) = W3T row c; col 256 = zero row).
constexpr int OFF_W1T  = 0;                      // 1025*256
constexpr int OFF_W23  = OFF_W1T + 1025*HID;     // 257*512
constexpr int OFF_WLI  = OFF_W23 + 257*512;      // [10][256]
constexpr int OFF_B1   = OFF_WLI + NCLS*HID;
constexpr int OFF_B2   = OFF_B1 + HID;
constexpr int OFF_B3   = OFF_B2 + HID;

// ---- LI readout linearized: vo_24 = sum_t coef[t] * (o3_t @ Wli^T).
struct CoefT { float c[TSTEPS]; };
constexpr CoefT make_coef() {
    CoefT r{};
    double c = 0.0, p9 = 1.0;
    r.c[TSTEPS-1] = 0.0f;
    for (int u = TSTEPS-1; u > 0; u--) {
        c = 0.8 * c + 0.1 * p9;
        p9 *= 0.9;
        r.c[u-1] = (float)c;
    }
    return r;
}
__device__ constexpr CoefT COEF = make_coef();

__device__ __forceinline__ u32 rfl(u32 v) {
    return (u32)__builtin_amdgcn_readfirstlane((int)v);   // pin wave-uniform -> SGPR
}

// ---- in-wave dtype detect: fp32 viewed as bf16 -> exponent garbage at even idx.
__device__ __forceinline__ u32 detect_bf16(const void* __restrict__ x, u32 lane) {
    float v = __bfloat162float(((const __hip_bfloat16*)x)[lane]);
    u64 bad = __ballot(!(fabsf(v) < 100.0f));
    return bad == 0ull ? 1u : 0u;
}

__device__ __forceinline__ float rd_any(const void* p, int idx, u32 isbf) {
    return isbf ? __bfloat162float(((const __hip_bfloat16*)p)[idx])
                : ((const float*)p)[idx];
}

__device__ __forceinline__ float4 rd4(const void* p, int i, u32 isbf) {
    if (isbf) {
        const u32* q = (const u32*)p;
        u32 a = q[i >> 1], b = q[(i >> 1) + 1];
        float4 r;
        r.x = __uint_as_float(a << 16); r.y = __uint_as_float(a & 0xffff0000u);
        r.z = __uint_as_float(b << 16); r.w = __uint_as_float(b & 0xffff0000u);
        return r;
    }
    return ((const float4*)p)[i >> 2];
}

// ---- prep: 32x32 LDS-tiled transpose, coalesced float4 both sides, 385 blocks.
__global__ __launch_bounds__(256) void prep_k(const void* __restrict__ x,
        const void* W1, const void* W2, const void* W3, const void* Wli,
        const void* b1, const void* b2, const void* b3, float* __restrict__ ws) {
    const u32 isbf = detect_bf16(x, threadIdx.x & 63);
    const u32 t = threadIdx.x;
    int b = blockIdx.x;

    if (b == 384) {   // tail: Wli + biases + zero rows (all coalesced)
        for (u32 e = t; e < NCLS*HID; e += 256) ws[OFF_WLI + e] = rd_any(Wli, e, isbf);
        ws[OFF_B1 + t] = rd_any(b1, t, isbf);
        ws[OFF_B2 + t] = rd_any(b2, t, isbf);
        ws[OFF_B3 + t] = rd_any(b3, t, isbf);
        ws[OFF_W1T + 1024*HID + t] = 0.f;
        ws[OFF_W23 + 256*512 + t] = 0.f;         // zero col 256, both halves
        ws[OFF_W23 + 256*512 + 256 + t] = 0.f;
        return;
    }

    const void* src; float* dst; int srcW, dstW, coff, h0, f0;
    if (b < 256)      { src = W1; dst = ws + OFF_W1T; srcW = FEAT; dstW = HID; coff = 0;
                        h0 = (b >> 5) * 32; f0 = (b & 31) * 32; }
    else if (b < 320) { int tb = b - 256; src = W2; dst = ws + OFF_W23; srcW = HID; dstW = 512; coff = 0;
                        h0 = (tb >> 3) * 32; f0 = (tb & 7) * 32; }
    else              { int tb = b - 320; src = W3; dst = ws + OFF_W23; srcW = HID; dstW = 512; coff = 256;
                        h0 = (tb >> 3) * 32; f0 = (tb & 7) * 32; }

    __shared__ float sm[32 * 36];
    {
        u32 r = t >> 3, c4 = (t & 7) * 4;
        float4 w = rd4(src, (h0 + r) * srcW + f0 + c4, isbf);
        *(float4*)&sm[r * 36 + c4] = w;
    }
    __syncthreads();
    {
        u32 f = t >> 3, h4 = (t & 7) * 4;
        float4 o;
        o.x = sm[(h4 + 0) * 36 + f];
        o.y = sm[(h4 + 1) * 36 + f];
        o.z = sm[(h4 + 2) * 36 + f];
        o.w = sm[(h4 + 3) * 36 + f];
        *(float4*)&dst[(size_t)(f0 + f) * dstW + coff + h0 + h4] = o;
    }
}

__device__ __forceinline__ u32 mbcnt64(u64 m) {
    return __builtin_amdgcn_mbcnt_hi((u32)(m >> 32),
           __builtin_amdgcn_mbcnt_lo((u32)m, 0u));
}

// ---- list builders: u16 col-index entries; branch-free prefix via weighted
// bit-plane ballots; pad to EVEN count with the zero-row col. ----

// encoder: 16 features/lane, col = 16*lane + j; zero col = 1024.
__device__ __forceinline__ u32 build_listE(u16* list, u32 lm, u32 lane) {
    u32 cnt = (u32)__builtin_popcount(lm);
    u32 pos = 0, n = 0;
    #pragma unroll
    for (int b = 0; b < 5; b++) {
        u64 B = __ballot(((cnt >> b) & 1u) != 0);
        pos += mbcnt64(B) << b;
        n += ((u32)__builtin_popcountll(B)) << b;
    }
    while (lm) {
        u32 j = (u32)__builtin_ctz(lm); lm &= lm - 1;
        list[pos++] = (u16)((lane << 4) + j);
    }
    u32 np = (n + 1u) & ~1u;
    if (lane == 0 && np != n) list[n] = (u16)1024;
    return np;
}

// z layers: 4 neurons/lane, col = 4*lane + j; zero col = 256; append at start
// (start must be even). returns padded end (even).
__device__ __forceinline__ u32 build_listZ(u16* list, u32 lm, u32 start, u32 lane) {
    u32 cnt = (u32)__builtin_popcount(lm);
    u64 B0 = __ballot((cnt & 1u) != 0);
    u64 B1 = __ballot((cnt & 2u) != 0);
    u64 B2 = __ballot((cnt & 4u) != 0);
    u32 pos = start + mbcnt64(B0) + 2u*mbcnt64(B1) + 4u*mbcnt64(B2);
    u32 n = start + (u32)__builtin_popcountll(B0) + 2u*(u32)__builtin_popcountll(B1)
          + 4u*(u32)__builtin_popcountll(B2);
    while (lm) {
        u32 j = (u32)__builtin_ctz(lm); lm &= lm - 1;
        list[pos++] = (u16)((lane << 2) + j);
    }
    u32 np = (n + 1u) & ~1u;
    if (lane == 0 && np != n) list[n] = (u16)256;
    return np;
}

#define GADD(AA, BB, V) do { AA += (v2f){(V).x, (V).y}; BB += (v2f){(V).z, (V).w}; } while (0)

// ---- gather (single matrix): chunks of 8 + 2-col tail; 4 independent
// accumulator chains. shl/disp select geometry (W1T: 10/0; W3 half: 11/1024). ----
__device__ __forceinline__ void gather(v2f& A, v2f& B, const char* __restrict__ base,
                                       const u16* __restrict__ list, u32 np, u32 lane16,
                                       const u32 shl, const u32 disp) {
    v2f Aa = {0.f,0.f}, Ba = {0.f,0.f}, Ab = {0.f,0.f}, Bb = {0.f,0.f};
    u32 c = 0;
    for (; c + 8 <= np; c += 8) {
        uint4 d = *(const uint4*)(list + c);
        u32 w0 = rfl(d.x), w1 = rfl(d.y), w2 = rfl(d.z), w3 = rfl(d.w);
        const float4 v0 = *(const float4*)(base + ((w0 & 0xffffu) << shl) + disp + lane16);
        const float4 v1 = *(const float4*)(base + ((w0 >> 16)     << shl) + disp + lane16);
        const float4 v2 = *(const float4*)(base + ((w1 & 0xffffu) << shl) + disp + lane16);
        const float4 v3 = *(const float4*)(base + ((w1 >> 16)     << shl) + disp + lane16);
        const float4 v4 = *(const float4*)(base + ((w2 & 0xffffu) << shl) + disp + lane16);
        const float4 v5 = *(const float4*)(base + ((w2 >> 16)     << shl) + disp + lane16);
        const float4 v6 = *(const float4*)(base + ((w3 & 0xffffu) << shl) + disp + lane16);
        const float4 v7 = *(const float4*)(base + ((w3 >> 16)     << shl) + disp + lane16);
        GADD(Aa, Ba, v0); GADD(Ab, Bb, v1); GADD(Aa, Ba, v2); GADD(Ab, Bb, v3);
        GADD(Aa, Ba, v4); GADD(Ab, Bb, v5); GADD(Aa, Ba, v6); GADD(Ab, Bb, v7);
    }
    for (; c < np; c += 2) {                      // 2-col units (4-B aligned)
        u32 d = rfl(*(const u32*)(list + c));
        const float4 v0 = *(const float4*)(base + ((d & 0xffffu) << shl) + disp + lane16);
        const float4 v1 = *(const float4*)(base + ((d >> 16)     << shl) + disp + lane16);
        GADD(Aa, Ba, v0); GADD(Ab, Bb, v1);
    }
    A += Aa + Ab; B += Ba + Bb;
}

// ---- dual gather over the z1 segment on the INTERLEAVED W23 matrix ----
__device__ __forceinline__ void gather_dual(v2f& A2, v2f& B2, v2f& A3, v2f& B3,
        const char* __restrict__ p, const u16* __restrict__ list, u32 np, u32 lane16) {
    u32 c = 0;
    for (; c + 4 <= np; c += 4) {
        uint2 d = *(const uint2*)(list + c);
        u32 w0 = rfl(d.x), w1 = rfl(d.y);
        u32 o0 = (w0 & 0xffffu) << 11, o1 = (w0 >> 16) << 11;
        u32 o2 = (w1 & 0xffffu) << 11, o3 = (w1 >> 16) << 11;
        const float4 a0 = *(const float4*)(p + o0 + lane16);
        const float4 a1 = *(const float4*)(p + o1 + lane16);
        const float4 a2 = *(const float4*)(p + o2 + lane16);
        const float4 a3 = *(const float4*)(p + o3 + lane16);
        const float4 c0 = *(const float4*)(p + o0 + 1024 + lane16);
        const float4 c1 = *(const float4*)(p + o1 + 1024 + lane16);
        const float4 c2 = *(const float4*)(p + o2 + 1024 + lane16);
        const float4 c3 = *(const float4*)(p + o3 + 1024 + lane16);
        GADD(A2, B2, a0); GADD(A2, B2, a1); GADD(A2, B2, a2); GADD(A2, B2, a3);
        GADD(A3, B3, c0); GADD(A3, B3, c1); GADD(A3, B3, c2); GADD(A3, B3, c3);
    }
    for (; c < np; c += 2) {
        u32 d = rfl(*(const u32*)(list + c));
        u32 o0 = (d & 0xffffu) << 11, o1 = (d >> 16) << 11;
        const float4 a0 = *(const float4*)(p + o0 + lane16);
        const float4 a1 = *(const float4*)(p + o1 + lane16);
        const float4 c0 = *(const float4*)(p + o0 + 1024 + lane16);
        const float4 c1 = *(const float4*)(p + o1 + 1024 + lane16);
        GADD(A2, B2, a0); GADD(A2, B2, a1);
        GADD(A3, B3, c0); GADD(A3, B3, c1);
    }
}

// ===== PIPELINED 2-WAVE SPLIT: one block = one row, wave A (w=0) = encoder +
// layer 1, wave B (w=1) = layers 2+3 + readout. Communication is ONE-WAY:
// A publishes the 256-bit z1 spike mask per step (4 ballots -> 32 B) into a
// 24-deep LDS ring and bumps a flag; B spin-waits (LDS poll + s_sleep).
// A never waits; no __syncthreads in the loop (rounds 1-3 showed bidirectional
// coupling loses; r4-r6 showed the kernel is per-wave-latency-bound at only
// 4 waves/SIMD). This gives 8192 waves = 32/CU (full residency) and cuts the
// slowest row's serial chain to ~max(A,B). Arithmetic is bit-identical: B
// reconstructs o1v in {0,1} from mask bits. =====
__global__ __launch_bounds__(128, 4) void snn_k(const void* __restrict__ xin,
                                                const float* __restrict__ ws,
                                                void* __restrict__ out,
                                                int batch) {
    const u32 tid  = threadIdx.x;
    const u32 w    = tid >> 6;                   // 0 = wave A, 1 = wave B
    const u32 lane = tid & 63;
    const int row  = blockIdx.x;
    if (row >= batch) return;                    // uniform per block
    const u32 lane16 = lane * 16;
    const u32 isbf = detect_bf16(xin, lane);

    const char* __restrict__ W1T = (const char*)(ws + OFF_W1T);
    const char* __restrict__ W23 = (const char*)(ws + OFF_W23);
    const float* __restrict__ WLI = ws + OFF_WLI;

    __shared__ u32 sched[12 * 64];               // 3072 B (A only)
    __shared__ __align__(16) u16 lE[1024];       // 2048 B (A only)
    __shared__ __align__(16) u16 lL[768];        // 1536 B (B only)
    __shared__ __align__(16) u64 ring[TSTEPS][4];// 768 B: z1 masks per step
    __shared__ u32 flagv;                        // steps completed by A

    if (tid == 0) flagv = 0;
    __syncthreads();                             // the ONLY barrier

    volatile u32* vf = &flagv;

    if (w == 0) {
        // ================= Wave A: encoder + layer 1 =================
        {
            float xv[16];
            if (isbf) {
                const uint4* xp = (const uint4*)((const u16*)xin + (size_t)row*FEAT + lane*16);
                uint4 A = xp[0], B = xp[1];
                u32 wd[8] = {A.x, A.y, A.z, A.w, B.x, B.y, B.z, B.w};
                #pragma unroll
                for (int i = 0; i < 8; i++) {
                    xv[2*i]   = __uint_as_float(wd[i] << 16);
                    xv[2*i+1] = __uint_as_float(wd[i] & 0xffff0000u);
                }
            } else {
                const float4* xp = (const float4*)((const float*)xin + (size_t)row*FEAT + lane*16);
                float4 A = xp[0], B = xp[1], C = xp[2], D = xp[3];
                float tmp[16] = {A.x,A.y,A.z,A.w,B.x,B.y,B.z,B.w,C.x,C.y,C.z,C.w,D.x,D.y,D.z,D.w};
                #pragma unroll
                for (int i = 0; i < 16; i++) xv[i] = tmp[i];
            }
            u32 smreg[12];
            #pragma unroll
            for (int i = 0; i < 12; i++) smreg[i] = 0;
            #pragma unroll
            for (int j = 0; j < 16; j++) {
                float v = 0.f;
                #pragma unroll
                for (int t = 0; t < TSTEPS; t++) {
                    v = v + 0.1f * (xv[j] - v);
                    bool z = v > 1.0f;
                    v = z ? 0.0f : v;
                    if (z) smreg[t >> 1] |= 1u << (((t & 1) << 4) + j);
                }
            }
            #pragma unroll
            for (int i = 0; i < 12; i++) sched[i * 64 + lane] = smreg[i];
            // lanes read back only their own words -> no barrier needed
        }

        float v1[4], i1[4];
        #pragma unroll
        for (int k = 0; k < 4; k++) { v1[k] = 0.f; i1[k] = 0.f; }
        const float4 b1v = *(const float4*)(ws + OFF_B1 + lane * 4);

        u32 pairreg = 0;
        for (int t = 0; t < TSTEPS; t++) {
            if ((t & 1) == 0) pairreg = sched[(t >> 1) * 64 + lane];
            const u32 lmE = (t & 1) ? (pairreg >> 16) : (pairreg & 0xffffu);

            v2f accA = {b1v.x, b1v.y}, accB = {b1v.z, b1v.w};
            if (__ballot(lmE != 0u)) {
                u32 npE = build_listE(lE, lmE, lane);
                gather(accA, accB, W1T, lE, npE, lane16, 10u, 0u);
            }
            float a1[4] = {accA.x, accA.y, accB.x, accB.y};

            u32 lm1 = 0;
            #pragma unroll
            for (int kk = 0; kk < 4; kk++) {
                float vd = v1[kk] + 0.1f * (i1[kk] - v1[kk]);
                i1[kk] = i1[kk] * 0.8f;
                bool z = vd > 0.23f;
                v1[kk] = z ? 0.0f : vd;
                i1[kk] = i1[kk] + a1[kk];
                lm1 |= (z ? 1u : 0u) << kk;
            }

            // publish z1 mask (4 bit-plane ballots -> 32 B) and bump flag
            u64 m0 = __ballot((lm1 & 1u) != 0);
            u64 m1 = __ballot((lm1 & 2u) != 0);
            u64 m2 = __ballot((lm1 & 4u) != 0);
            u64 m3 = __ballot((lm1 & 8u) != 0);
            if (lane == 0) {
                ring[t][0] = m0; ring[t][1] = m1; ring[t][2] = m2; ring[t][3] = m3;
                __threadfence_block();           // masks visible before flag
                *vf = (u32)(t + 1);
            }
        }
    } else {
        // ============ Wave B: layers 2+3 + linearized readout ============
        float v2[4], i2[4], v3[4], i3[4], g[4];
        #pragma unroll
        for (int k = 0; k < 4; k++) { v2[k]=0.f; i2[k]=0.f; v3[k]=0.f; i3[k]=0.f; g[k]=0.f; }
        const u32 lane4 = lane * 4;
        const float4 b2v = *(const float4*)(ws + OFF_B2 + lane4);
        const float4 b3v = *(const float4*)(ws + OFF_B3 + lane4);

        u32 seen = 0;
        for (int t = 0; t < TSTEPS; t++) {
            if (seen < (u32)(t + 1)) {
                do { seen = *vf; } while (seen < (u32)(t + 1));
            }
            __threadfence_block();               // acquire: no hoisting of ring reads
            const volatile u64* rp = ring[t];
            u64 m0 = rp[0], m1 = rp[1], m2 = rp[2], m3 = rp[3];
            u32 lm1 = (u32)((m0 >> lane) & 1ull)
                    | ((u32)((m1 >> lane) & 1ull) << 1)
                    | ((u32)((m2 >> lane) & 1ull) << 2)
                    | ((u32)((m3 >> lane) & 1ull) << 3);
            float o1v[4];
            #pragma unroll
            for (int kk = 0; kk < 4; kk++) o1v[kk] = (lm1 >> kk) & 1u ? 1.0f : 0.0f;

            // ---- layers 2+3a: z1 cols, dual gather on interleaved W23 ----
            v2f acc2A = {b2v.x, b2v.y}, acc2B = {b2v.z, b2v.w};
            v2f acc3A = {b3v.x, b3v.y}, acc3B = {b3v.z, b3v.w};
            u32 np1 = 0;
            if (__ballot(lm1 != 0u)) {
                np1 = build_listZ(lL, lm1, 0u, lane);
                gather_dual(acc2A, acc2B, acc3A, acc3B, W23, lL, np1, lane16);
            }
            float a2[4] = {acc2A.x, acc2A.y, acc2B.x, acc2B.y};

            float o2v[4]; u32 lm2 = 0;
            #pragma unroll
            for (int kk = 0; kk < 4; kk++) {
                float vd = v2[kk] + 0.1f * (i2[kk] - v2[kk]);
                i2[kk] = i2[kk] * 0.8f;
                bool z = vd > 0.23f;
                v2[kk] = z ? 0.0f : vd;
                i2[kk] = i2[kk] + a2[kk];
                o2v[kk] = (z ? 1.0f : 0.0f) + o1v[kk];
                lm2 |= (z ? 1u : 0u) << kk;
            }

            // ---- layer 3b: append z2 at padded np1, gather on W3 half ----
            if (__ballot(lm2 != 0u)) {
                u32 np2 = build_listZ(lL, lm2, np1, lane);
                gather(acc3A, acc3B, W23, lL + np1, np2 - np1, lane16, 11u, 1024u);
            }
            float a3[4] = {acc3A.x, acc3A.y, acc3B.x, acc3B.y};

            const float cf = COEF.c[t];
            #pragma unroll
            for (int kk = 0; kk < 4; kk++) {
                float vd = v3[kk] + 0.1f * (i3[kk] - v3[kk]);
                i3[kk] = i3[kk] * 0.8f;
                bool z = vd > 0.23f;
                v3[kk] = z ? 0.0f : vd;
                i3[kk] = i3[kk] + a3[kk];
                float o3 = (z ? 1.0f : 0.0f) + o2v[kk];
                g[kk] += cf * o3;
            }
        }

        // ---- epilogue: vo_24[c] = sum_h g[h]*Wli[c][h] ----
        float s[NCLS];
        #pragma unroll
        for (int c = 0; c < NCLS; c++) {
            const float4 wv = *(const float4*)(WLI + c*HID + lane4);
            float p = g[0]*wv.x + g[1]*wv.y + g[2]*wv.z + g[3]*wv.w;
            #pragma unroll
            for (int d = 32; d > 0; d >>= 1) p += __shfl_xor(p, d, 64);
            s[c] = p;
        }
        if (lane == 0) {
            if (isbf) {
                __hip_bfloat16* o = (__hip_bfloat16*)out + (size_t)row*NCLS;
                #pragma unroll
                for (int c = 0; c < NCLS; c++) o[c] = __float2bfloat16(s[c]);
            } else {
                float* o = (float*)out + (size_t)row*NCLS;
                #pragma unroll
                for (int c = 0; c < NCLS; c++) o[c] = s[c];
            }
        }
    }
}

extern "C" void kernel_launch(void* const* d_in, const int* in_sizes, int n_in,
                              void* d_out, int out_size, void* d_ws, size_t ws_size,
                              hipStream_t stream) {
    const void* x   = d_in[0];
    const void* W1  = d_in[1];
    const void* b1  = d_in[2];
    const void* W2  = d_in[3];
    const void* b2  = d_in[4];
    const void* W3  = d_in[5];
    const void* b3  = d_in[6];
    const void* Wli = d_in[7];
    float* ws = (float*)d_ws;
    const int batch = in_sizes[0] / FEAT;   // 4096

    prep_k<<<385, 256, 0, stream>>>(x, W1, W2, W3, Wli, b1, b2, b3, ws);
    snn_k<<<batch, 128, 0, stream>>>(x, ws, d_out, batch);
}

// Round 9
// 155.750 us; speedup vs baseline: 1.0741x; 1.0741x over previous
//
#include <hip/hip_runtime.h>
#include <hip/hip_bf16.h>

#define FEAT   1024
#define HID    256
#define TSTEPS 24
#define NCLS   10

typedef unsigned int u32;
typedef unsigned long long u64;
typedef unsigned short u16;
typedef float v2f __attribute__((ext_vector_type(2)));

// ---- workspace layout (float offsets).
// W1T: [1025][256] (W1^T + zero row at col 1024).
// W23: [257][512]  INTERLEAVED W2^T | W3^T per column (col c: floats [0,256) =
//      W2T row c, [256,512) = W3T row c; col 256 = zero row).
constexpr int OFF_W1T  = 0;                      // 1025*256
constexpr int OFF_W23  = OFF_W1T + 1025*HID;     // 257*512
constexpr int OFF_WLI  = OFF_W23 + 257*512;      // [10][256]
constexpr int OFF_B1   = OFF_WLI + NCLS*HID;
constexpr int OFF_B2   = OFF_B1 + HID;
constexpr int OFF_B3   = OFF_B2 + HID;

// ---- LI readout linearized: vo_24 = sum_t coef[t] * (o3_t @ Wli^T).
struct CoefT { float c[TSTEPS]; };
constexpr CoefT make_coef() {
    CoefT r{};
    double c = 0.0, p9 = 1.0;
    r.c[TSTEPS-1] = 0.0f;
    for (int u = TSTEPS-1; u > 0; u--) {
        c = 0.8 * c + 0.1 * p9;
        p9 *= 0.9;
        r.c[u-1] = (float)c;
    }
    return r;
}
__device__ constexpr CoefT COEF = make_coef();

__device__ __forceinline__ u32 rfl(u32 v) {
    return (u32)__builtin_amdgcn_readfirstlane((int)v);   // pin wave-uniform -> SGPR
}

// ---- in-wave dtype detect: fp32 viewed as bf16 -> exponent garbage at even idx.
__device__ __forceinline__ u32 detect_bf16(const void* __restrict__ x, u32 lane) {
    float v = __bfloat162float(((const __hip_bfloat16*)x)[lane]);
    u64 bad = __ballot(!(fabsf(v) < 100.0f));
    return bad == 0ull ? 1u : 0u;
}

__device__ __forceinline__ float rd_any(const void* p, int idx, u32 isbf) {
    return isbf ? __bfloat162float(((const __hip_bfloat16*)p)[idx])
                : ((const float*)p)[idx];
}

__device__ __forceinline__ float4 rd4(const void* p, int i, u32 isbf) {
    if (isbf) {
        const u32* q = (const u32*)p;
        u32 a = q[i >> 1], b = q[(i >> 1) + 1];
        float4 r;
        r.x = __uint_as_float(a << 16); r.y = __uint_as_float(a & 0xffff0000u);
        r.z = __uint_as_float(b << 16); r.w = __uint_as_float(b & 0xffff0000u);
        return r;
    }
    return ((const float4*)p)[i >> 2];
}

// ---- prep: 32x32 LDS-tiled transpose, coalesced float4 both sides, 385 blocks.
__global__ __launch_bounds__(256) void prep_k(const void* __restrict__ x,
        const void* W1, const void* W2, const void* W3, const void* Wli,
        const void* b1, const void* b2, const void* b3, float* __restrict__ ws) {
    const u32 isbf = detect_bf16(x, threadIdx.x & 63);
    const u32 t = threadIdx.x;
    int b = blockIdx.x;

    if (b == 384) {   // tail: Wli + biases + zero rows (all coalesced)
        for (u32 e = t; e < NCLS*HID; e += 256) ws[OFF_WLI + e] = rd_any(Wli, e, isbf);
        ws[OFF_B1 + t] = rd_any(b1, t, isbf);
        ws[OFF_B2 + t] = rd_any(b2, t, isbf);
        ws[OFF_B3 + t] = rd_any(b3, t, isbf);
        ws[OFF_W1T + 1024*HID + t] = 0.f;
        ws[OFF_W23 + 256*512 + t] = 0.f;         // zero col 256, both halves
        ws[OFF_W23 + 256*512 + 256 + t] = 0.f;
        return;
    }

    const void* src; float* dst; int srcW, dstW, coff, h0, f0;
    if (b < 256)      { src = W1; dst = ws + OFF_W1T; srcW = FEAT; dstW = HID; coff = 0;
                        h0 = (b >> 5) * 32; f0 = (b & 31) * 32; }
    else if (b < 320) { int tb = b - 256; src = W2; dst = ws + OFF_W23; srcW = HID; dstW = 512; coff = 0;
                        h0 = (tb >> 3) * 32; f0 = (tb & 7) * 32; }
    else              { int tb = b - 320; src = W3; dst = ws + OFF_W23; srcW = HID; dstW = 512; coff = 256;
                        h0 = (tb >> 3) * 32; f0 = (tb & 7) * 32; }

    __shared__ float sm[32 * 36];
    {
        u32 r = t >> 3, c4 = (t & 7) * 4;
        float4 w = rd4(src, (h0 + r) * srcW + f0 + c4, isbf);
        *(float4*)&sm[r * 36 + c4] = w;
    }
    __syncthreads();
    {
        u32 f = t >> 3, h4 = (t & 7) * 4;
        float4 o;
        o.x = sm[(h4 + 0) * 36 + f];
        o.y = sm[(h4 + 1) * 36 + f];
        o.z = sm[(h4 + 2) * 36 + f];
        o.w = sm[(h4 + 3) * 36 + f];
        *(float4*)&dst[(size_t)(f0 + f) * dstW + coff + h0 + h4] = o;
    }
}

__device__ __forceinline__ u32 mbcnt64(u64 m) {
    return __builtin_amdgcn_mbcnt_hi((u32)(m >> 32),
           __builtin_amdgcn_mbcnt_lo((u32)m, 0u));
}

// ---- list builders: u16 col-index entries; branch-free prefix via weighted
// bit-plane ballots; pad to EVEN count with the zero-row col. ----

// encoder: 16 features/lane, col = 16*lane + j; zero col = 1024.
__device__ __forceinline__ u32 build_listE(u16* list, u32 lm, u32 lane) {
    u32 cnt = (u32)__builtin_popcount(lm);
    u32 pos = 0, n = 0;
    #pragma unroll
    for (int b = 0; b < 5; b++) {
        u64 B = __ballot(((cnt >> b) & 1u) != 0);
        pos += mbcnt64(B) << b;
        n += ((u32)__builtin_popcountll(B)) << b;
    }
    while (lm) {
        u32 j = (u32)__builtin_ctz(lm); lm &= lm - 1;
        list[pos++] = (u16)((lane << 4) + j);
    }
    u32 np = (n + 1u) & ~1u;
    if (lane == 0 && np != n) list[n] = (u16)1024;
    return np;
}

// z layers: 4 neurons/lane, col = 4*lane + j; zero col = 256; append at start
// (start must be even). returns padded end (even).
__device__ __forceinline__ u32 build_listZ(u16* list, u32 lm, u32 start, u32 lane) {
    u32 cnt = (u32)__builtin_popcount(lm);
    u64 B0 = __ballot((cnt & 1u) != 0);
    u64 B1 = __ballot((cnt & 2u) != 0);
    u64 B2 = __ballot((cnt & 4u) != 0);
    u32 pos = start + mbcnt64(B0) + 2u*mbcnt64(B1) + 4u*mbcnt64(B2);
    u32 n = start + (u32)__builtin_popcountll(B0) + 2u*(u32)__builtin_popcountll(B1)
          + 4u*(u32)__builtin_popcountll(B2);
    while (lm) {
        u32 j = (u32)__builtin_ctz(lm); lm &= lm - 1;
        list[pos++] = (u16)((lane << 2) + j);
    }
    u32 np = (n + 1u) & ~1u;
    if (lane == 0 && np != n) list[n] = (u16)256;
    return np;
}

#define GADD(AA, BB, V) do { AA += (v2f){(V).x, (V).y}; BB += (v2f){(V).z, (V).w}; } while (0)

// ---- gather (single list): chunks of 8 + 2-col tail; 4 independent chains.
// shl/disp select geometry (W1T: 10/0; W2 half of W23: 11/0; W3 half: 11/1024). ----
__device__ __forceinline__ void gather(v2f& A, v2f& B, const char* __restrict__ base,
                                       const u16* __restrict__ list, u32 np, u32 lane16,
                                       const u32 shl, const u32 disp) {
    v2f Aa = {0.f,0.f}, Ba = {0.f,0.f}, Ab = {0.f,0.f}, Bb = {0.f,0.f};
    u32 c = 0;
    for (; c + 8 <= np; c += 8) {
        uint4 d = *(const uint4*)(list + c);
        u32 w0 = rfl(d.x), w1 = rfl(d.y), w2 = rfl(d.z), w3 = rfl(d.w);
        const float4 v0 = *(const float4*)(base + ((w0 & 0xffffu) << shl) + disp + lane16);
        const float4 v1 = *(const float4*)(base + ((w0 >> 16)     << shl) + disp + lane16);
        const float4 v2 = *(const float4*)(base + ((w1 & 0xffffu) << shl) + disp + lane16);
        const float4 v3 = *(const float4*)(base + ((w1 >> 16)     << shl) + disp + lane16);
        const float4 v4 = *(const float4*)(base + ((w2 & 0xffffu) << shl) + disp + lane16);
        const float4 v5 = *(const float4*)(base + ((w2 >> 16)     << shl) + disp + lane16);
        const float4 v6 = *(const float4*)(base + ((w3 & 0xffffu) << shl) + disp + lane16);
        const float4 v7 = *(const float4*)(base + ((w3 >> 16)     << shl) + disp + lane16);
        GADD(Aa, Ba, v0); GADD(Ab, Bb, v1); GADD(Aa, Ba, v2); GADD(Ab, Bb, v3);
        GADD(Aa, Ba, v4); GADD(Ab, Bb, v5); GADD(Aa, Ba, v6); GADD(Ab, Bb, v7);
    }
    for (; c < np; c += 2) {                      // 2-col units (4-B aligned)
        u32 d = rfl(*(const u32*)(list + c));
        const float4 v0 = *(const float4*)(base + ((d & 0xffffu) << shl) + disp + lane16);
        const float4 v1 = *(const float4*)(base + ((d >> 16)     << shl) + disp + lane16);
        GADD(Aa, Ba, v0); GADD(Ab, Bb, v1);
    }
    A += Aa + Ab; B += Ba + Bb;
}

// ---- gather2: TWO independent lists (two timesteps) on the same matrix,
// interleaved 4-col chunks -> 8 loads from 2 independent streams in flight;
// each stream's inter-chunk bubble (LDS list read + saddr setup) hides under
// the other stream's vmcnt waits. Drains via gather(). ----
__device__ __forceinline__ void gather2(v2f& A0, v2f& B0, v2f& A1, v2f& B1,
        const char* __restrict__ base,
        const u16* __restrict__ la, u32 na,
        const u16* __restrict__ lb, u32 nb,
        u32 lane16, const u32 shl, const u32 disp) {
    u32 ca = 0, cb = 0;
    while (ca + 4 <= na && cb + 4 <= nb) {
        uint2 da = *(const uint2*)(la + ca);
        uint2 db = *(const uint2*)(lb + cb);
        u32 wa0 = rfl(da.x), wa1 = rfl(da.y);
        u32 wb0 = rfl(db.x), wb1 = rfl(db.y);
        const float4 va0 = *(const float4*)(base + ((wa0 & 0xffffu) << shl) + disp + lane16);
        const float4 va1 = *(const float4*)(base + ((wa0 >> 16)     << shl) + disp + lane16);
        const float4 va2 = *(const float4*)(base + ((wa1 & 0xffffu) << shl) + disp + lane16);
        const float4 va3 = *(const float4*)(base + ((wa1 >> 16)     << shl) + disp + lane16);
        const float4 vb0 = *(const float4*)(base + ((wb0 & 0xffffu) << shl) + disp + lane16);
        const float4 vb1 = *(const float4*)(base + ((wb0 >> 16)     << shl) + disp + lane16);
        const float4 vb2 = *(const float4*)(base + ((wb1 & 0xffffu) << shl) + disp + lane16);
        const float4 vb3 = *(const float4*)(base + ((wb1 >> 16)     << shl) + disp + lane16);
        GADD(A0, B0, va0); GADD(A0, B0, va1); GADD(A0, B0, va2); GADD(A0, B0, va3);
        GADD(A1, B1, vb0); GADD(A1, B1, vb1); GADD(A1, B1, vb2); GADD(A1, B1, vb3);
        ca += 4; cb += 4;
    }
    gather(A0, B0, base, la + ca, na - ca, lane16, shl, disp);
    gather(A1, B1, base, lb + cb, nb - cb, lane16, shl, disp);
}

// LIF recurrence for 4 neurons (in-place v,i; returns spike mask via lmout).
#define LIF_STEP(vv, ii, aa, lmout) do {                                   \
    lmout = 0;                                                             \
    _Pragma("unroll")                                                      \
    for (int kk = 0; kk < 4; kk++) {                                       \
        float vd = vv[kk] + 0.1f * (ii[kk] - vv[kk]);                      \
        ii[kk] = ii[kk] * 0.8f;                                            \
        bool z = vd > 0.23f;                                               \
        vv[kk] = z ? 0.0f : vd;                                            \
        ii[kk] = ii[kk] + aa[kk];                                          \
        lmout |= (z ? 1u : 0u) << kk;                                      \
    } } while (0)

// ===== PHASE-SEPARATED, PAIR-PIPELINED: one wave = one row. The network's
// serial chain is only through the cheap VALU recurrences; the GATHERS of
// different timesteps within a layer are independent once that layer's input
// masks are known. So: phase 1 = layer 1 for all 24 steps (encoder masks known
// upfront), phase 2 = layer 2 (z1 masks known after phase 1), phase 3 = layer
// 3 + readout (z1,z2 known). Each phase processes steps in PAIRS with an
// interleaved dual-stream gather -> 2x memory-level parallelism, inter-chunk
// bubbles of one stream hidden under the other's loads. Spike masks carried
// between phases in 3 u32 registers per layer (4 bits/step, static-indexed
// via unrolled 8-step blocks). Evidence r4-r7: occupancy/bytes/dep-chain/
// cross-wave levers all null or negative; this attacks the chain across TIME
// within one wave, the only untried axis. (Resubmit of round 8 — the bench
// failed on container infra, not kernel verification.) =====
__global__ __launch_bounds__(64, 4) void snn_k(const void* __restrict__ xin,
                                               const float* __restrict__ ws,
                                               void* __restrict__ out,
                                               int batch) {
    const u32 lane = threadIdx.x;
    const int row  = blockIdx.x;
    if (row >= batch) return;
    const u32 lane16 = lane * 16;
    const u32 isbf = detect_bf16(xin, lane);

    const char* __restrict__ W1T = (const char*)(ws + OFF_W1T);
    const char* __restrict__ W23 = (const char*)(ws + OFF_W23);
    const float* __restrict__ WLI = ws + OFF_WLI;

    __shared__ u32 sched[12 * 64];               // 3072 B: encoder masks, 2 steps/u32
    __shared__ __align__(16) u16 lbA[1040];      // 2080 B: list buffer, stream A
    __shared__ __align__(16) u16 lbB[1040];      // 2080 B: list buffer, stream B

    // ---- phase 0: encoder sim -> 24-step spike schedule for my 16 features ----
    {
        float xv[16];
        if (isbf) {
            const uint4* xp = (const uint4*)((const u16*)xin + (size_t)row*FEAT + lane*16);
            uint4 A = xp[0], B = xp[1];
            u32 wd[8] = {A.x, A.y, A.z, A.w, B.x, B.y, B.z, B.w};
            #pragma unroll
            for (int i = 0; i < 8; i++) {
                xv[2*i]   = __uint_as_float(wd[i] << 16);
                xv[2*i+1] = __uint_as_float(wd[i] & 0xffff0000u);
            }
        } else {
            const float4* xp = (const float4*)((const float*)xin + (size_t)row*FEAT + lane*16);
            float4 A = xp[0], B = xp[1], C = xp[2], D = xp[3];
            float tmp[16] = {A.x,A.y,A.z,A.w,B.x,B.y,B.z,B.w,C.x,C.y,C.z,C.w,D.x,D.y,D.z,D.w};
            #pragma unroll
            for (int i = 0; i < 16; i++) xv[i] = tmp[i];
        }
        u32 smreg[12];
        #pragma unroll
        for (int i = 0; i < 12; i++) smreg[i] = 0;
        #pragma unroll
        for (int j = 0; j < 16; j++) {
            float v = 0.f;
            #pragma unroll
            for (int t = 0; t < TSTEPS; t++) {
                v = v + 0.1f * (xv[j] - v);
                bool z = v > 1.0f;
                v = z ? 0.0f : v;
                if (z) smreg[t >> 1] |= 1u << (((t & 1) << 4) + j);
            }
        }
        #pragma unroll
        for (int i = 0; i < 12; i++) sched[i * 64 + lane] = smreg[i];
        // lanes read back only their own words -> no barrier needed
    }

    u32 m1[3], m2[3];                            // per-lane z1/z2 masks, 4 bits/step

    // ================= phase 1: layer 1, all 24 steps in pairs =================
    {
        float v1[4], i1[4];
        #pragma unroll
        for (int k = 0; k < 4; k++) { v1[k] = 0.f; i1[k] = 0.f; }
        const float4 b1v = *(const float4*)(ws + OFF_B1 + lane * 4);

        #pragma unroll
        for (int blk = 0; blk < 3; blk++) {
            u32 mw = 0;
            #pragma unroll 1
            for (int pr = 0; pr < 4; pr++) {
                u32 pairreg = sched[(blk*4 + pr) * 64 + lane];
                u32 lmEa = pairreg & 0xffffu, lmEb = pairreg >> 16;

                v2f aA = {b1v.x, b1v.y}, aB = {b1v.z, b1v.w};
                v2f cA = {b1v.x, b1v.y}, cB = {b1v.z, b1v.w};
                u32 na = 0, nb = 0;
                if (__ballot(lmEa != 0u)) na = build_listE(lbA, lmEa, lane);
                if (__ballot(lmEb != 0u)) nb = build_listE(lbB, lmEb, lane);
                gather2(aA, aB, cA, cB, W1T, lbA, na, lbB, nb, lane16, 10u, 0u);

                float a1a[4] = {aA.x, aA.y, aB.x, aB.y};
                u32 lma; LIF_STEP(v1, i1, a1a, lma);
                mw |= lma << (pr * 8);

                float a1b[4] = {cA.x, cA.y, cB.x, cB.y};
                u32 lmb; LIF_STEP(v1, i1, a1b, lmb);
                mw |= lmb << (pr * 8 + 4);
            }
            m1[blk] = mw;
        }
    }

    // ================= phase 2: layer 2, all 24 steps in pairs =================
    {
        float v2[4], i2[4];
        #pragma unroll
        for (int k = 0; k < 4; k++) { v2[k] = 0.f; i2[k] = 0.f; }
        const float4 b2v = *(const float4*)(ws + OFF_B2 + lane * 4);

        #pragma unroll
        for (int blk = 0; blk < 3; blk++) {
            const u32 w1 = m1[blk];
            u32 mw = 0;
            #pragma unroll 1
            for (int pr = 0; pr < 4; pr++) {
                u32 lmA = (w1 >> (pr * 8)) & 0xFu;
                u32 lmB = (w1 >> (pr * 8 + 4)) & 0xFu;

                v2f aA = {b2v.x, b2v.y}, aB = {b2v.z, b2v.w};
                v2f cA = {b2v.x, b2v.y}, cB = {b2v.z, b2v.w};
                u32 na = 0, nb = 0;
                if (__ballot(lmA != 0u)) na = build_listZ(lbA, lmA, 0u, lane);
                if (__ballot(lmB != 0u)) nb = build_listZ(lbB, lmB, 0u, lane);
                gather2(aA, aB, cA, cB, W23, lbA, na, lbB, nb, lane16, 11u, 0u);

                float a2a[4] = {aA.x, aA.y, aB.x, aB.y};
                u32 lma; LIF_STEP(v2, i2, a2a, lma);
                mw |= lma << (pr * 8);

                float a2b[4] = {cA.x, cA.y, cB.x, cB.y};
                u32 lmb; LIF_STEP(v2, i2, a2b, lmb);
                mw |= lmb << (pr * 8 + 4);
            }
            m2[blk] = mw;
        }
    }

    // ======== phase 3: layer 3 (+ linearized readout), pairs; list per step =
    //          z1 segment [0,np1) then z2 segment [np1,np2) (o2 = z1 + z2 via
    //          duplicate cols, exact) ========
    float g[4];
    #pragma unroll
    for (int k = 0; k < 4; k++) g[k] = 0.f;
    {
        float v3[4], i3[4];
        #pragma unroll
        for (int k = 0; k < 4; k++) { v3[k] = 0.f; i3[k] = 0.f; }
        const float4 b3v = *(const float4*)(ws + OFF_B3 + lane * 4);

        #pragma unroll
        for (int blk = 0; blk < 3; blk++) {
            const u32 w1 = m1[blk], w2 = m2[blk];
            #pragma unroll 1
            for (int pr = 0; pr < 4; pr++) {
                const int t0 = blk * 8 + pr * 2;
                u32 lmA1 = (w1 >> (pr * 8)) & 0xFu,  lmA2 = (w2 >> (pr * 8)) & 0xFu;
                u32 lmB1 = (w1 >> (pr * 8 + 4)) & 0xFu, lmB2 = (w2 >> (pr * 8 + 4)) & 0xFu;

                v2f aA = {b3v.x, b3v.y}, aB = {b3v.z, b3v.w};
                v2f cA = {b3v.x, b3v.y}, cB = {b3v.z, b3v.w};
                u32 na = 0, nb = 0;
                if (__ballot(lmA1 != 0u)) na = build_listZ(lbA, lmA1, 0u, lane);
                if (__ballot(lmA2 != 0u)) na = build_listZ(lbA, lmA2, na, lane);
                if (__ballot(lmB1 != 0u)) nb = build_listZ(lbB, lmB1, 0u, lane);
                if (__ballot(lmB2 != 0u)) nb = build_listZ(lbB, lmB2, nb, lane);
                gather2(aA, aB, cA, cB, W23, lbA, na, lbB, nb, lane16, 11u, 1024u);

                // step t0
                {
                    float a3[4] = {aA.x, aA.y, aB.x, aB.y};
                    const float cf = COEF.c[t0];
                    #pragma unroll
                    for (int kk = 0; kk < 4; kk++) {
                        float vd = v3[kk] + 0.1f * (i3[kk] - v3[kk]);
                        i3[kk] = i3[kk] * 0.8f;
                        bool z = vd > 0.23f;
                        v3[kk] = z ? 0.0f : vd;
                        i3[kk] = i3[kk] + a3[kk];
                        float o2 = (float)((lmA1 >> kk) & 1u) + (float)((lmA2 >> kk) & 1u);
                        float o3 = (z ? 1.0f : 0.0f) + o2;
                        g[kk] += cf * o3;
                    }
                }
                // step t0+1
                {
                    float a3[4] = {cA.x, cA.y, cB.x, cB.y};
                    const float cf = COEF.c[t0 + 1];
                    #pragma unroll
                    for (int kk = 0; kk < 4; kk++) {
                        float vd = v3[kk] + 0.1f * (i3[kk] - v3[kk]);
                        i3[kk] = i3[kk] * 0.8f;
                        bool z = vd > 0.23f;
                        v3[kk] = z ? 0.0f : vd;
                        i3[kk] = i3[kk] + a3[kk];
                        float o2 = (float)((lmB1 >> kk) & 1u) + (float)((lmB2 >> kk) & 1u);
                        float o3 = (z ? 1.0f : 0.0f) + o2;
                        g[kk] += cf * o3;
                    }
                }
            }
        }
    }

    // ---- epilogue: vo_24[c] = sum_h g[h]*Wli[c][h] ----
    const u32 lane4 = lane * 4;
    float s[NCLS];
    #pragma unroll
    for (int c = 0; c < NCLS; c++) {
        const float4 wv = *(const float4*)(WLI + c*HID + lane4);
        float p = g[0]*wv.x + g[1]*wv.y + g[2]*wv.z + g[3]*wv.w;
        #pragma unroll
        for (int d = 32; d > 0; d >>= 1) p += __shfl_xor(p, d, 64);
        s[c] = p;
    }
    if (lane == 0) {
        if (isbf) {
            __hip_bfloat16* o = (__hip_bfloat16*)out + (size_t)row*NCLS;
            #pragma unroll
            for (int c = 0; c < NCLS; c++) o[c] = __float2bfloat16(s[c]);
        } else {
            float* o = (float*)out + (size_t)row*NCLS;
            #pragma unroll
            for (int c = 0; c < NCLS; c++) o[c] = s[c];
        }
    }
}

extern "C" void kernel_launch(void* const* d_in, const int* in_sizes, int n_in,
                              void* d_out, int out_size, void* d_ws, size_t ws_size,
                              hipStream_t stream) {
    const void* x   = d_in[0];
    const void* W1  = d_in[1];
    const void* b1  = d_in[2];
    const void* W2  = d_in[3];
    const void* b2  = d_in[4];
    const void* W3  = d_in[5];
    const void* b3  = d_in[6];
    const void* Wli = d_in[7];
    float* ws = (float*)d_ws;
    const int batch = in_sizes[0] / FEAT;   // 4096

    prep_k<<<385, 256, 0, stream>>>(x, W1, W2, W3, Wli, b1, b2, b3, ws);
    snn_k<<<batch, 64, 0, stream>>>(x, ws, d_out, batch);
}